// Round 1
// 612.015 us; speedup vs baseline: 1.0609x; 1.0609x over previous
//
#include <hip/hip_runtime.h>

// ---------- bf16 helpers (raw ushort representation) ----------
__device__ __forceinline__ float bf2f(unsigned short u) {
    union { unsigned int i; float f; } v;
    v.i = ((unsigned int)u) << 16;
    return v.f;
}
__device__ __forceinline__ unsigned short f2bf(float f) {
    union { float f; unsigned int i; } v;
    v.f = f;
    unsigned int r = (v.i + 0x7fffu + ((v.i >> 16) & 1u)) >> 16;
    return (unsigned short)r;
}

typedef __attribute__((ext_vector_type(8))) short short8;
typedef __attribute__((ext_vector_type(4))) float floatx4;

#define GLOBAL_AS __attribute__((address_space(1)))
#define LDS_AS __attribute__((address_space(3)))

static constexpr int Bdim = 8;
static constexpr int Tdim = 2048;
static constexpr int Cdim = 1024;
static constexpr int Edim = 4096;
static constexpr int Mdim = Bdim * Tdim;  // 16384

// ---------- weight transpose + cast: src fp32 (K x N) -> dst bf16 (N x K) ----------
__global__ __launch_bounds__(256) void transpose_f2b(
    const float* __restrict__ src, unsigned short* __restrict__ dst, int K, int N) {
    __shared__ float tile[32][33];
    int n0 = blockIdx.x * 32;
    int k0 = blockIdx.y * 32;
    int tx = threadIdx.x & 31;
    int ty = threadIdx.x >> 5;  // 0..7
#pragma unroll
    for (int i = 0; i < 32; i += 8)
        tile[ty + i][tx] = src[(size_t)(k0 + ty + i) * N + n0 + tx];
    __syncthreads();
#pragma unroll
    for (int i = 0; i < 32; i += 8)
        dst[(size_t)(n0 + ty + i) * K + k0 + tx] = f2bf(tile[tx][ty + i]);
}

// ---------- rmsnorm1 inverse-RMS only: rinv[row] = rsqrt(mean(x^2)+eps) ----------
__global__ __launch_bounds__(256) void rms_inv_kernel(
    const float* __restrict__ x, float* __restrict__ rinv) {
    int row = blockIdx.x;
    int tid = threadIdx.x;
    float4 v = ((const float4*)(x + (size_t)row * Cdim))[tid];
    float s = v.x * v.x + v.y * v.y + v.z * v.z + v.w * v.w;
#pragma unroll
    for (int o = 32; o > 0; o >>= 1) s += __shfl_down(s, o, 64);
    __shared__ float ps[4];
    if ((tid & 63) == 0) ps[tid >> 6] = s;
    __syncthreads();
    if (tid == 0) {
        float tot = ps[0] + ps[1] + ps[2] + ps[3];
        rinv[row] = rsqrtf(tot * (1.0f / (float)Cdim) + 1e-6f);
    }
}

// ---------- cumsum phase A: per-chunk sums of y = x*rinv*w. 1024 blocks ----------
__global__ __launch_bounds__(256) void chunk_sums(
    const float* __restrict__ x, const float* __restrict__ rinv,
    const float* __restrict__ w, float* __restrict__ P) {
    int idx = blockIdx.x;
    int cb = idx & 3;
    int k = (idx >> 2) & 31;
    int b = idx >> 7;
    int c = cb * 256 + threadIdx.x;
    float wc = w[c];
    const float* base = x + ((size_t)b * Tdim + k * 64) * Cdim + c;
    const float* rbase = rinv + (size_t)b * Tdim + k * 64;
    float s = 0.f;
#pragma unroll 8
    for (int t = 0; t < 64; t++) s += base[(size_t)t * Cdim] * rbase[t];
    P[((size_t)b * 32 + k) * Cdim + c] = s * wc;
}

// ---------- cumsum phase B: exclusive scan of 32 chunk sums per (b,c) chain ----------
__global__ __launch_bounds__(256) void chunk_scan(float* __restrict__ P) {
    int g = blockIdx.x * 256 + threadIdx.x;  // 0..8191
    int b = g >> 10;
    int c = g & 1023;
    float* p = P + (size_t)b * 32 * Cdim + c;
    float run = 0.f;
#pragma unroll
    for (int k = 0; k < 32; k++) {
        float v = p[(size_t)k * Cdim];
        p[(size_t)k * Cdim] = run;
        run += v;
    }
}

// ---------- cumsum phase C: rescan, divide by triangular scaler, emit bf16 state ----------
__global__ __launch_bounds__(256) void cumsum_state(
    const float* __restrict__ x, const float* __restrict__ rinv,
    const float* __restrict__ w, const float* __restrict__ P,
    unsigned short* __restrict__ state) {
    int idx = blockIdx.x;
    int cb = idx & 3;
    int k = (idx >> 2) & 31;
    int b = idx >> 7;
    int c = cb * 256 + threadIdx.x;
    float wc = w[c];
    float acc = P[((size_t)b * 32 + k) * Cdim + c];
    const float* base = x + ((size_t)b * Tdim + k * 64) * Cdim + c;
    const float* rbase = rinv + (size_t)b * Tdim + k * 64;
    unsigned short* sbase = state + ((size_t)b * Tdim + k * 64) * Cdim + c;
#pragma unroll 4
    for (int t = 0; t < 64; t++) {
        acc += base[(size_t)t * Cdim] * rbase[t] * wc;
        int tt = k * 64 + t;
        float inv = 2.0f / ((float)(tt + 1) * (float)(tt + 2));
        sbase[(size_t)t * Cdim] = f2bf(acc * inv);
    }
}

// ---------- rmsnorm2: fp32 in -> bf16 out (GEMM A operand) ----------
__global__ __launch_bounds__(256) void rmsnorm_f2b(
    const float* __restrict__ x, const float* __restrict__ w,
    unsigned short* __restrict__ y) {
    int row = blockIdx.x;
    int tid = threadIdx.x;
    float4 v = ((const float4*)(x + (size_t)row * Cdim))[tid];
    float s = v.x * v.x + v.y * v.y + v.z * v.z + v.w * v.w;
#pragma unroll
    for (int o = 32; o > 0; o >>= 1) s += __shfl_down(s, o, 64);
    __shared__ float ps[4];
    if ((tid & 63) == 0) ps[tid >> 6] = s;
    __syncthreads();
    float tot = ps[0] + ps[1] + ps[2] + ps[3];
    float r = rsqrtf(tot * (1.0f / (float)Cdim) + 1e-6f);
    float4 w4 = ((const float4*)w)[tid];
    ushort4 o;
    o.x = f2bf(v.x * r * w4.x);
    o.y = f2bf(v.y * r * w4.y);
    o.z = f2bf(v.z * r * w4.z);
    o.w = f2bf(v.w * r * w4.w);
    ((ushort4*)(y + (size_t)row * Cdim))[tid] = o;
}

// ---------- bf16 MFMA GEMM: 256x128 tile, BK=64, 3-buffer counted-vmcnt pipeline ----
// C(MxN) = A(MxK) @ BT^T. 512 threads = 8 waves (4M x 2N), per-wave output 128x64.
// Pipeline invariants (race-freedom by construction):
//  * Stages for K-tile t+2 go to buf (t+2)%3 == buf of tile t-1, whose last ds_read
//    completed at tile t-1's final lgkmcnt(0), >=2 barriers before the stage issue.
//    -> WAR impossible; no half-tile stagger deadlines needed.
//  * 6 global_load_lds per K-tile per wave; every wave executes s_waitcnt vmcnt(6)
//    BEFORE the K-tile-boundary barrier -> after the barrier, tile t+1's slices from
//    ALL waves have landed; tile t+2's 6 loads stay in flight (never drain to 0).
//  * LDS XOR-swizzle col8 ^= (row&7): ds_read_b128 lanes 0-15 (16 rows, same slot)
//    spread across all 8 16B slots -> 2-way aliasing (free). global_load_lds writes
//    linearly; the swizzle is applied by permuting the per-lane GLOBAL source addr.
template <int EPI>
__global__ __launch_bounds__(512, 2) void gemm8(
    const unsigned short* __restrict__ A, const unsigned short* __restrict__ BT,
    const float* __restrict__ bias, const float* __restrict__ extra,
    void* __restrict__ Coutv, int N, int K) {
    __shared__ __attribute__((aligned(16))) unsigned short As[3][256 * 64];
    __shared__ __attribute__((aligned(16))) unsigned short Bs[3][128 * 64];

    int tid = threadIdx.x;
    int nbn = N >> 7;
    int id = blockIdx.x;
    int nwg = gridDim.x;
    // XCD-aware swizzle: XCD x gets a contiguous chunk of block ids -> A-panel reuse
    // stays within one XCD's L2. All grids here are divisible by 8.
    if ((nwg & 7) == 0) id = (id & 7) * (nwg >> 3) + (id >> 3);
    int bn = id % nbn;
    int bm = id / nbn;

    int lane = tid & 63;
    int w = tid >> 6;
    int wm = w & 3;   // M quarter: rows wm*64 .. +63  (within 256)
    int wn = w >> 2;  // N half:  cols wn*64 .. +63  (within 128)
    int lrow = lane & 15;
    int l4 = lane >> 4;   // 0..3
    int swz = lrow & 7;   // row&7 for all fragment rows (i*16 preserves低 3 bits)

    const unsigned short* Abase = A + (size_t)bm * 256 * K;
    const unsigned short* Bbase = BT + (size_t)bn * 128 * K;

    // staging: unit u = 64 rows x 64 cols (8KB). thread t covers row u*64 + t/8,
    // 16B block (t&7), with pre-swizzled source column so LDS dest stays linear.
    int sr = tid >> 3;                   // row within unit
    int col8 = (tid & 7) ^ (sr & 7);     // swizzled source 8-elem column block

#define STAGE_A(sb, u, k0)                                                               \
    __builtin_amdgcn_global_load_lds(                                                    \
        (const GLOBAL_AS void*)(Abase + (size_t)((u) * 64 + sr) * K + (k0) + col8 * 8),  \
        (LDS_AS void*)(As[sb] + (u) * 4096 + tid * 8), 16, 0, 0)
#define STAGE_B(sb, u, k0)                                                               \
    __builtin_amdgcn_global_load_lds(                                                    \
        (const GLOBAL_AS void*)(Bbase + (size_t)((u) * 64 + sr) * K + (k0) + col8 * 8),  \
        (LDS_AS void*)(Bs[sb] + (u) * 4096 + tid * 8), 16, 0, 0)

    floatx4 acc[4][4] = {};
    int nt = K >> 6;

    // prologue: stage K-tiles 0 (buf0) and 1 (buf1); wait for tile 0 only.
    STAGE_A(0, 0, 0); STAGE_A(0, 1, 0); STAGE_A(0, 2, 0); STAGE_A(0, 3, 0);
    STAGE_B(0, 0, 0); STAGE_B(0, 1, 0);
    STAGE_A(1, 0, 64); STAGE_A(1, 1, 64); STAGE_A(1, 2, 64); STAGE_A(1, 3, 64);
    STAGE_B(1, 0, 64); STAGE_B(1, 1, 64);
    asm volatile("s_waitcnt vmcnt(6)" ::: "memory");
    __builtin_amdgcn_s_barrier();

    int buf = 0;
    for (int t = 0; t < nt; t++) {
        const unsigned short* Ab = As[buf];
        const unsigned short* Bb = Bs[buf];
        int sb = buf + 2; if (sb >= 3) sb -= 3;
        int k2 = (t + 2) << 6;
        bool st = (t + 2) < nt;

        short8 af[4][2], bfr[2][2];
        // ---- phase A: all 8 A-frags + B-frags N0,N1 (12 ds_read_b128); stage 3 units
#pragma unroll
        for (int i = 0; i < 4; i++)
#pragma unroll
            for (int ks = 0; ks < 2; ks++)
                af[i][ks] = *(const short8*)(Ab + (wm * 64 + i * 16 + lrow) * 64 +
                                             (((ks * 4 + l4) ^ swz) << 3));
#pragma unroll
        for (int j = 0; j < 2; j++)
#pragma unroll
            for (int ks = 0; ks < 2; ks++)
                bfr[j][ks] = *(const short8*)(Bb + (wn * 64 + j * 16 + lrow) * 64 +
                                              (((ks * 4 + l4) ^ swz) << 3));
        if (st) { STAGE_A(sb, 0, k2); STAGE_A(sb, 1, k2); STAGE_A(sb, 2, k2); }
        asm volatile("s_waitcnt lgkmcnt(8)" ::: "memory");
        __builtin_amdgcn_s_barrier();
        asm volatile("s_waitcnt lgkmcnt(0)" ::: "memory");
        __builtin_amdgcn_s_setprio(1);
#pragma unroll
        for (int i = 0; i < 4; i++)
#pragma unroll
            for (int j = 0; j < 2; j++)
#pragma unroll
                for (int ks = 0; ks < 2; ks++)
                    acc[i][j] = __builtin_amdgcn_mfma_f32_16x16x32_bf16(
                        af[i][ks], bfr[j][ks], acc[i][j], 0, 0, 0);
        __builtin_amdgcn_s_setprio(0);
        __builtin_amdgcn_s_barrier();

        // ---- phase B: B-frags N2,N3 (4 ds_read_b128); stage remaining 3 units
#pragma unroll
        for (int j = 0; j < 2; j++)
#pragma unroll
            for (int ks = 0; ks < 2; ks++)
                bfr[j][ks] = *(const short8*)(Bb + (wn * 64 + (j + 2) * 16 + lrow) * 64 +
                                              (((ks * 4 + l4) ^ swz) << 3));
        if (st) { STAGE_A(sb, 3, k2); STAGE_B(sb, 0, k2); STAGE_B(sb, 1, k2); }
        __builtin_amdgcn_s_barrier();
        asm volatile("s_waitcnt lgkmcnt(0)" ::: "memory");
        __builtin_amdgcn_s_setprio(1);
#pragma unroll
        for (int i = 0; i < 4; i++)
#pragma unroll
            for (int j = 0; j < 2; j++)
#pragma unroll
                for (int ks = 0; ks < 2; ks++)
                    acc[i][j + 2] = __builtin_amdgcn_mfma_f32_16x16x32_bf16(
                        af[i][ks], bfr[j][ks], acc[i][j + 2], 0, 0, 0);
        __builtin_amdgcn_s_setprio(0);
        // K-tile boundary guard: tile t+1 must be fully landed for ALL waves after the
        // barrier. Counted vmcnt(6) leaves tile t+2's loads in flight. Epilogue of the
        // stream (no t+2 staged) must drain instead.
        if (t + 1 < nt) {
            if (st) asm volatile("s_waitcnt vmcnt(6)" ::: "memory");
            else    asm volatile("s_waitcnt vmcnt(0)" ::: "memory");
        }
        __builtin_amdgcn_s_barrier();

        buf++; if (buf == 3) buf = 0;
    }
#undef STAGE_A
#undef STAGE_B

    // epilogue: C/D layout col=lane&15, row=(lane>>4)*4+reg
    int crow = l4 << 2;
    int ccol = lane & 15;
#pragma unroll
    for (int i = 0; i < 4; i++) {
#pragma unroll
        for (int j = 0; j < 4; j++) {
            size_t gm = (size_t)bm * 256 + wm * 64 + i * 16 + crow;
            size_t gn = (size_t)bn * 128 + wn * 64 + j * 16 + ccol;
            float bsv = bias[gn];
#pragma unroll
            for (int r = 0; r < 4; r++) {
                float v = acc[i][j][r] + bsv;
                size_t off = (gm + r) * (size_t)N + gn;
                if (EPI == 0) {
                    float g = 1.f / (1.f + __expf(-v));
                    ((float*)Coutv)[off] = g * extra[off];
                } else if (EPI == 1) {
                    ((unsigned short*)Coutv)[off] = f2bf(v > 0.f ? v : 0.f);
                } else {
                    ((float*)Coutv)[off] = v + extra[off];
                }
            }
        }
    }
}

// ---------- launch ----------
extern "C" void kernel_launch(void* const* d_in, const int* in_sizes, int n_in,
                              void* d_out, int out_size, void* d_ws, size_t ws_size,
                              hipStream_t stream) {
    const float* x   = (const float*)d_in[0];  // (B,T,C) fp32
    const float* n1w = (const float*)d_in[1];  // (C)
    const float* w1  = (const float*)d_in[2];  // (C,C)
    const float* b1  = (const float*)d_in[3];  // (C)
    const float* n2w = (const float*)d_in[4];  // (C)
    const float* w21 = (const float*)d_in[5];  // (C,E)
    const float* b21 = (const float*)d_in[6];  // (E)
    const float* w22 = (const float*)d_in[7];  // (E,C)
    const float* b22 = (const float*)d_in[8];  // (C)
    float* out = (float*)d_out;                // (B,T,C) fp32

    char* ws = (char*)d_ws;
    const size_t MB = 1024ull * 1024ull;
    unsigned short* state = (unsigned short*)(ws);            // 32MB bf16; reused as hnorm
    unsigned short* w1T   = (unsigned short*)(ws + 32 * MB);  // 2MB  (C x C) bf16
    unsigned short* w21T  = (unsigned short*)(ws + 34 * MB);  // 8MB  (E x C) bf16
    unsigned short* w22T  = (unsigned short*)(ws + 42 * MB);  // 8MB  (C x E) bf16
    float* P              = (float*)(ws + 50 * MB);           // 1MB
    float* rinv           = (float*)(ws + 51 * MB);           // 64KB
    unsigned short* h     = (unsigned short*)(ws + 52 * MB);  // up to 128MB bf16 (sliced)
    float* out1 = out;  // gate*x lives in d_out (fp32); G3 reads then overwrites per-element

    // pick M-slice size for the h buffer based on available workspace
    int slice_rows = Mdim;  // 16384 -> h=128MB (total 180MB); halve until it fits
    while (52 * MB + (size_t)slice_rows * Edim * 2 > ws_size && slice_rows > 1024)
        slice_rows >>= 1;

    // weights -> bf16 (N x K)
    transpose_f2b<<<dim3(Cdim / 32, Cdim / 32), 256, 0, stream>>>(w1, w1T, Cdim, Cdim);
    transpose_f2b<<<dim3(Edim / 32, Cdim / 32), 256, 0, stream>>>(w21, w21T, Cdim, Edim);
    transpose_f2b<<<dim3(Cdim / 32, Edim / 32), 256, 0, stream>>>(w22, w22T, Edim, Cdim);

    // rmsnorm1 scale factors
    rms_inv_kernel<<<Mdim, 256, 0, stream>>>(x, rinv);

    // chunked cumsum of x*rinv*n1w over T, with triangular scaler -> bf16 state
    chunk_sums<<<1024, 256, 0, stream>>>(x, rinv, n1w, P);
    chunk_scan<<<32, 256, 0, stream>>>(P);
    cumsum_state<<<1024, 256, 0, stream>>>(x, rinv, n1w, P, state);

    // G1: out1 = sigmoid(state @ w1 + b1) * x   (fp32 out into d_out)
    gemm8<0><<<dim3((Mdim / 256) * (Cdim / 128)), 512, 0, stream>>>(
        state, w1T, b1, x, out1, Cdim, Cdim);

    // rmsnorm2(out1) -> bf16 hnorm (reuse state buffer)
    rmsnorm_f2b<<<Mdim, 256, 0, stream>>>(out1, n2w, state);

    // G2/G3 sliced over M to bound the h buffer
    for (int m0 = 0; m0 < Mdim; m0 += slice_rows) {
        gemm8<1><<<dim3((slice_rows / 256) * (Edim / 128)), 512, 0, stream>>>(
            state + (size_t)m0 * Cdim, w21T, b21, nullptr, h, Edim, Cdim);
        gemm8<2><<<dim3((slice_rows / 256) * (Cdim / 128)), 512, 0, stream>>>(
            h, w22T, b22, out1 + (size_t)m0 * Cdim, out + (size_t)m0 * Cdim,
            Cdim, Edim);
    }
}

// Round 2
// 561.801 us; speedup vs baseline: 1.1558x; 1.0894x over previous
//
#include <hip/hip_runtime.h>

// ---------- bf16 helpers (raw ushort representation) ----------
__device__ __forceinline__ float bf2f(unsigned short u) {
    union { unsigned int i; float f; } v;
    v.i = ((unsigned int)u) << 16;
    return v.f;
}
__device__ __forceinline__ unsigned short f2bf(float f) {
    union { float f; unsigned int i; } v;
    v.f = f;
    unsigned int r = (v.i + 0x7fffu + ((v.i >> 16) & 1u)) >> 16;
    return (unsigned short)r;
}

typedef __attribute__((ext_vector_type(8))) short short8;
typedef __attribute__((ext_vector_type(4))) float floatx4;

#define GLOBAL_AS __attribute__((address_space(1)))
#define LDS_AS __attribute__((address_space(3)))

static constexpr int Bdim = 8;
static constexpr int Tdim = 2048;
static constexpr int Cdim = 1024;
static constexpr int Edim = 4096;
static constexpr int Mdim = Bdim * Tdim;  // 16384

// ---------- weight transpose + cast: src fp32 (K x N) -> dst bf16 (N x K) ----------
__global__ __launch_bounds__(256) void transpose_f2b(
    const float* __restrict__ src, unsigned short* __restrict__ dst, int K, int N) {
    __shared__ float tile[32][33];
    int n0 = blockIdx.x * 32;
    int k0 = blockIdx.y * 32;
    int tx = threadIdx.x & 31;
    int ty = threadIdx.x >> 5;  // 0..7
#pragma unroll
    for (int i = 0; i < 32; i += 8)
        tile[ty + i][tx] = src[(size_t)(k0 + ty + i) * N + n0 + tx];
    __syncthreads();
#pragma unroll
    for (int i = 0; i < 32; i += 8)
        dst[(size_t)(n0 + ty + i) * K + k0 + tx] = f2bf(tile[tx][ty + i]);
}

// ---------- rmsnorm1 inverse-RMS only: rinv[row] = rsqrt(mean(x^2)+eps) ----------
__global__ __launch_bounds__(256) void rms_inv_kernel(
    const float* __restrict__ x, float* __restrict__ rinv) {
    int row = blockIdx.x;
    int tid = threadIdx.x;
    float4 v = ((const float4*)(x + (size_t)row * Cdim))[tid];
    float s = v.x * v.x + v.y * v.y + v.z * v.z + v.w * v.w;
#pragma unroll
    for (int o = 32; o > 0; o >>= 1) s += __shfl_down(s, o, 64);
    __shared__ float ps[4];
    if ((tid & 63) == 0) ps[tid >> 6] = s;
    __syncthreads();
    if (tid == 0) {
        float tot = ps[0] + ps[1] + ps[2] + ps[3];
        rinv[row] = rsqrtf(tot * (1.0f / (float)Cdim) + 1e-6f);
    }
}

// ---------- cumsum phase A: per-chunk sums of y = x*rinv*w. 1024 blocks ----------
__global__ __launch_bounds__(256) void chunk_sums(
    const float* __restrict__ x, const float* __restrict__ rinv,
    const float* __restrict__ w, float* __restrict__ P) {
    int idx = blockIdx.x;
    int cb = idx & 3;
    int k = (idx >> 2) & 31;
    int b = idx >> 7;
    int c = cb * 256 + threadIdx.x;
    float wc = w[c];
    const float* base = x + ((size_t)b * Tdim + k * 64) * Cdim + c;
    const float* rbase = rinv + (size_t)b * Tdim + k * 64;
    float s = 0.f;
#pragma unroll 8
    for (int t = 0; t < 64; t++) s += base[(size_t)t * Cdim] * rbase[t];
    P[((size_t)b * 32 + k) * Cdim + c] = s * wc;
}

// ---------- cumsum phase B: exclusive scan of 32 chunk sums per (b,c) chain ----------
__global__ __launch_bounds__(256) void chunk_scan(float* __restrict__ P) {
    int g = blockIdx.x * 256 + threadIdx.x;  // 0..8191
    int b = g >> 10;
    int c = g & 1023;
    float* p = P + (size_t)b * 32 * Cdim + c;
    float run = 0.f;
#pragma unroll
    for (int k = 0; k < 32; k++) {
        float v = p[(size_t)k * Cdim];
        p[(size_t)k * Cdim] = run;
        run += v;
    }
}

// ---------- cumsum phase C: rescan, divide by triangular scaler, emit bf16 state ----------
__global__ __launch_bounds__(256) void cumsum_state(
    const float* __restrict__ x, const float* __restrict__ rinv,
    const float* __restrict__ w, const float* __restrict__ P,
    unsigned short* __restrict__ state) {
    int idx = blockIdx.x;
    int cb = idx & 3;
    int k = (idx >> 2) & 31;
    int b = idx >> 7;
    int c = cb * 256 + threadIdx.x;
    float wc = w[c];
    float acc = P[((size_t)b * 32 + k) * Cdim + c];
    const float* base = x + ((size_t)b * Tdim + k * 64) * Cdim + c;
    const float* rbase = rinv + (size_t)b * Tdim + k * 64;
    unsigned short* sbase = state + ((size_t)b * Tdim + k * 64) * Cdim + c;
#pragma unroll 4
    for (int t = 0; t < 64; t++) {
        acc += base[(size_t)t * Cdim] * rbase[t] * wc;
        int tt = k * 64 + t;
        float inv = 2.0f / ((float)(tt + 1) * (float)(tt + 2));
        sbase[(size_t)t * Cdim] = f2bf(acc * inv);
    }
}

// ---------- rmsnorm2: fp32 in -> bf16 out (GEMM A operand) ----------
__global__ __launch_bounds__(256) void rmsnorm_f2b(
    const float* __restrict__ x, const float* __restrict__ w,
    unsigned short* __restrict__ y) {
    int row = blockIdx.x;
    int tid = threadIdx.x;
    float4 v = ((const float4*)(x + (size_t)row * Cdim))[tid];
    float s = v.x * v.x + v.y * v.y + v.z * v.z + v.w * v.w;
#pragma unroll
    for (int o = 32; o > 0; o >>= 1) s += __shfl_down(s, o, 64);
    __shared__ float ps[4];
    if ((tid & 63) == 0) ps[tid >> 6] = s;
    __syncthreads();
    float tot = ps[0] + ps[1] + ps[2] + ps[3];
    float r = rsqrtf(tot * (1.0f / (float)Cdim) + 1e-6f);
    float4 w4 = ((const float4*)w)[tid];
    ushort4 o;
    o.x = f2bf(v.x * r * w4.x);
    o.y = f2bf(v.y * r * w4.y);
    o.z = f2bf(v.z * r * w4.z);
    o.w = f2bf(v.w * r * w4.w);
    ((ushort4*)(y + (size_t)row * Cdim))[tid] = o;
}

// ---------- bf16 MFMA GEMM: 256x256 tile, BK=64, 8-phase counted-vmcnt pipeline ----
// C(MxN) = A(MxK) @ BT^T. 512 threads = 8 waves (2M x 4N), per-wave output 128x64,
// acc[8][4]. 2 LDS buffers (buf t&1 holds K-tile t), 128 KiB total.
// Per iteration j: 8 phases compute K-tiles 2j (buf0, ph0-3) and 2j+1 (buf1, ph4-7).
// Each phase: {4-8 ds_read_b128 | stage ONE half-tile (2 global_load_lds) | barrier |
//              lgkmcnt(0) | setprio(1) 16 MFMA setprio(0) | barrier}.
// Stagger (WAR-free: each staged region's last ds_read completed >=1 barrier earlier):
//   ph0: A-lo(2j+1)  ph1: A-hi(2j+1)   [buf1 A freed at prev ph7]
//   ph2: B-lo(2j+2)  ph3: B-hi(2j+2)   [buf0 B read only at ph0/ph1]
//   ph4: A-lo(2j+2)  ph5: A-hi(2j+2)   [buf0 A read through ph3]
//   ph6: B-lo(2j+3)  ph7: B-hi(2j+3)   [buf1 B read only at ph4/ph5]
// vmcnt(4) ONLY at end of ph3 and ph7: 12 load-instr outstanding, drain to newest 4
// (the next B-tile) -> the consumed tile is fully landed, newest stays in flight.
// LDS XOR-swizzle slot^=(row&7) via pre-swizzled global source (linear LDS dest).
template <int EPI>
__global__ __launch_bounds__(512, 2) void gemm8(
    const unsigned short* __restrict__ A, const unsigned short* __restrict__ BT,
    const float* __restrict__ bias, const float* __restrict__ extra,
    void* __restrict__ Coutv, int N, int K) {
    __shared__ __attribute__((aligned(16))) unsigned short As[2][256 * 64];
    __shared__ __attribute__((aligned(16))) unsigned short Bs[2][256 * 64];

    int tid = threadIdx.x;
    int nbn = N >> 8;
    int id = blockIdx.x;
    int nwg = gridDim.x;
    // XCD-aware swizzle (all grids divisible by 8): contiguous chunk per XCD.
    if ((nwg & 7) == 0) id = (id & 7) * (nwg >> 3) + (id >> 3);
    int bn = id % nbn;
    int bm = id / nbn;

    int lane = tid & 63;
    int w = tid >> 6;     // 0..7
    int wm = w >> 2;      // 0..1 : rows wm*128 .. +127
    int wn = w & 3;       // 0..3 : cols wn*64 .. +63
    int lrow = lane & 15;
    int l4 = lane >> 4;   // 0..3
    int swz = lrow & 7;
    int wmB = wm * 128, wnB = wn * 64;

    const unsigned short* Abase = A + (size_t)bm * 256 * K;
    const unsigned short* Bbase = BT + (size_t)bn * 256 * K;

    // staging: unit u = 64 rows x 64 cols (8KB) = 1 global_load_lds per thread.
    // source column pre-swizzled so the linear LDS dest ends up XOR-swizzled.
    int sr = tid >> 3;                 // row within unit
    int col8 = (tid & 7) ^ (sr & 7);   // swizzled source 8-elem column block

#define STAGE_A(sb, u, k0)                                                               \
    __builtin_amdgcn_global_load_lds(                                                    \
        (const GLOBAL_AS void*)(Abase + (size_t)((u) * 64 + sr) * K + (k0) + col8 * 8),  \
        (LDS_AS void*)(As[sb] + (u) * 4096 + tid * 8), 16, 0, 0)
#define STAGE_B(sb, u, k0)                                                               \
    __builtin_amdgcn_global_load_lds(                                                    \
        (const GLOBAL_AS void*)(Bbase + (size_t)((u) * 64 + sr) * K + (k0) + col8 * 8),  \
        (LDS_AS void*)(Bs[sb] + (u) * 4096 + tid * 8), 16, 0, 0)

    // fragment reads (swizzled slot)
#define LDA(cb, i, ks)                                                                   \
    (*(const short8*)(As[cb] + (wmB + (i) * 16 + lrow) * 64 + ((((ks) * 4 + l4) ^ swz) << 3)))
#define LDB(cb, jj, ks)                                                                  \
    (*(const short8*)(Bs[cb] + (wnB + (jj) * 16 + lrow) * 64 + ((((ks) * 4 + l4) ^ swz) << 3)))

#define PH_IN                                                                            \
    do {                                                                                 \
        __builtin_amdgcn_s_barrier();                                                    \
        asm volatile("s_waitcnt lgkmcnt(0)" ::: "memory");                               \
        __builtin_amdgcn_s_setprio(1);                                                   \
    } while (0)
#define PH_OUT                                                                           \
    do {                                                                                 \
        __builtin_amdgcn_s_setprio(0);                                                   \
        __builtin_amdgcn_s_barrier();                                                    \
    } while (0)

    floatx4 acc[8][4] = {};
    int nt = K >> 6;       // K-tiles (even: K is a multiple of 128 here)
    int nIter = nt >> 1;

    // prologue: A(0), B(0) fully; B(1) fully. vmcnt(4): tile 0 landed, B(1) in flight.
    STAGE_A(0, 0, 0); STAGE_A(0, 1, 0); STAGE_A(0, 2, 0); STAGE_A(0, 3, 0);
    STAGE_B(0, 0, 0); STAGE_B(0, 1, 0); STAGE_B(0, 2, 0); STAGE_B(0, 3, 0);
    STAGE_B(1, 0, 64); STAGE_B(1, 1, 64); STAGE_B(1, 2, 64); STAGE_B(1, 3, 64);
    asm volatile("s_waitcnt vmcnt(4)" ::: "memory");
    __builtin_amdgcn_s_barrier();

    for (int j = 0; j < nIter; ++j) {
        int k1 = (2 * j + 1) << 6;
        int k2 = (2 * j + 2) << 6;
        int k3 = (2 * j + 3) << 6;
        bool nl = (j + 1 < nIter);

        short8 av[4], b0[4], b1[4];

        // ---- ph0: tile 2j, wave rows 0-63, ks=0 ----
#pragma unroll
        for (int i = 0; i < 4; i++) av[i] = LDA(0, i, 0);
#pragma unroll
        for (int i = 0; i < 4; i++) b0[i] = LDB(0, i, 0);
        STAGE_A(1, 0, k1); STAGE_A(1, 1, k1);
        PH_IN;
#pragma unroll
        for (int i = 0; i < 4; i++)
#pragma unroll
            for (int q = 0; q < 4; q++)
                acc[i][q] = __builtin_amdgcn_mfma_f32_16x16x32_bf16(av[i], b0[q], acc[i][q], 0, 0, 0);
        PH_OUT;

        // ---- ph1: tile 2j, wave rows 0-63, ks=1 ----
#pragma unroll
        for (int i = 0; i < 4; i++) av[i] = LDA(0, i, 1);
#pragma unroll
        for (int i = 0; i < 4; i++) b1[i] = LDB(0, i, 1);
        STAGE_A(1, 2, k1); STAGE_A(1, 3, k1);
        PH_IN;
#pragma unroll
        for (int i = 0; i < 4; i++)
#pragma unroll
            for (int q = 0; q < 4; q++)
                acc[i][q] = __builtin_amdgcn_mfma_f32_16x16x32_bf16(av[i], b1[q], acc[i][q], 0, 0, 0);
        PH_OUT;

        // ---- ph2: tile 2j, wave rows 64-127, ks=0 (b0 reused) ----
#pragma unroll
        for (int i = 0; i < 4; i++) av[i] = LDA(0, 4 + i, 0);
        if (nl) { STAGE_B(0, 0, k2); STAGE_B(0, 1, k2); }
        PH_IN;
#pragma unroll
        for (int i = 0; i < 4; i++)
#pragma unroll
            for (int q = 0; q < 4; q++)
                acc[4 + i][q] = __builtin_amdgcn_mfma_f32_16x16x32_bf16(av[i], b0[q], acc[4 + i][q], 0, 0, 0);
        PH_OUT;

        // ---- ph3: tile 2j, wave rows 64-127, ks=1 (b1 reused); vmcnt gate ----
#pragma unroll
        for (int i = 0; i < 4; i++) av[i] = LDA(0, 4 + i, 1);
        if (nl) { STAGE_B(0, 2, k2); STAGE_B(0, 3, k2); }
        PH_IN;
#pragma unroll
        for (int i = 0; i < 4; i++)
#pragma unroll
            for (int q = 0; q < 4; q++)
                acc[4 + i][q] = __builtin_amdgcn_mfma_f32_16x16x32_bf16(av[i], b1[q], acc[4 + i][q], 0, 0, 0);
        __builtin_amdgcn_s_setprio(0);
        if (nl) asm volatile("s_waitcnt vmcnt(4)" ::: "memory");
        else    asm volatile("s_waitcnt vmcnt(0)" ::: "memory");
        __builtin_amdgcn_s_barrier();

        // ---- ph4: tile 2j+1, wave rows 0-63, ks=0 ----
#pragma unroll
        for (int i = 0; i < 4; i++) av[i] = LDA(1, i, 0);
#pragma unroll
        for (int i = 0; i < 4; i++) b0[i] = LDB(1, i, 0);
        if (nl) { STAGE_A(0, 0, k2); STAGE_A(0, 1, k2); }
        PH_IN;
#pragma unroll
        for (int i = 0; i < 4; i++)
#pragma unroll
            for (int q = 0; q < 4; q++)
                acc[i][q] = __builtin_amdgcn_mfma_f32_16x16x32_bf16(av[i], b0[q], acc[i][q], 0, 0, 0);
        PH_OUT;

        // ---- ph5: tile 2j+1, wave rows 0-63, ks=1 ----
#pragma unroll
        for (int i = 0; i < 4; i++) av[i] = LDA(1, i, 1);
#pragma unroll
        for (int i = 0; i < 4; i++) b1[i] = LDB(1, i, 1);
        if (nl) { STAGE_A(0, 2, k2); STAGE_A(0, 3, k2); }
        PH_IN;
#pragma unroll
        for (int i = 0; i < 4; i++)
#pragma unroll
            for (int q = 0; q < 4; q++)
                acc[i][q] = __builtin_amdgcn_mfma_f32_16x16x32_bf16(av[i], b1[q], acc[i][q], 0, 0, 0);
        PH_OUT;

        // ---- ph6: tile 2j+1, wave rows 64-127, ks=0 ----
#pragma unroll
        for (int i = 0; i < 4; i++) av[i] = LDA(1, 4 + i, 0);
        if (nl) { STAGE_B(1, 0, k3); STAGE_B(1, 1, k3); }
        PH_IN;
#pragma unroll
        for (int i = 0; i < 4; i++)
#pragma unroll
            for (int q = 0; q < 4; q++)
                acc[4 + i][q] = __builtin_amdgcn_mfma_f32_16x16x32_bf16(av[i], b0[q], acc[4 + i][q], 0, 0, 0);
        PH_OUT;

        // ---- ph7: tile 2j+1, wave rows 64-127, ks=1; vmcnt gate ----
#pragma unroll
        for (int i = 0; i < 4; i++) av[i] = LDA(1, 4 + i, 1);
        if (nl) { STAGE_B(1, 2, k3); STAGE_B(1, 3, k3); }
        PH_IN;
#pragma unroll
        for (int i = 0; i < 4; i++)
#pragma unroll
            for (int q = 0; q < 4; q++)
                acc[4 + i][q] = __builtin_amdgcn_mfma_f32_16x16x32_bf16(av[i], b1[q], acc[4 + i][q], 0, 0, 0);
        __builtin_amdgcn_s_setprio(0);
        if (nl) asm volatile("s_waitcnt vmcnt(4)" ::: "memory");
        __builtin_amdgcn_s_barrier();
    }
#undef STAGE_A
#undef STAGE_B
#undef LDA
#undef LDB
#undef PH_IN
#undef PH_OUT

    // epilogue: C/D layout col=lane&15, row=(lane>>4)*4+reg
    int crow = l4 << 2;
    int ccol = lane & 15;
#pragma unroll
    for (int i = 0; i < 8; i++) {
#pragma unroll
        for (int q = 0; q < 4; q++) {
            size_t gm = (size_t)bm * 256 + wmB + i * 16 + crow;
            size_t gn = (size_t)bn * 256 + wnB + q * 16 + ccol;
            float bsv = bias[gn];
#pragma unroll
            for (int r = 0; r < 4; r++) {
                float v = acc[i][q][r] + bsv;
                size_t off = (gm + r) * (size_t)N + gn;
                if (EPI == 0) {
                    float g = 1.f / (1.f + __expf(-v));
                    ((float*)Coutv)[off] = g * extra[off];
                } else if (EPI == 1) {
                    ((unsigned short*)Coutv)[off] = f2bf(v > 0.f ? v : 0.f);
                } else {
                    ((float*)Coutv)[off] = v + extra[off];
                }
            }
        }
    }
}

// ---------- launch ----------
extern "C" void kernel_launch(void* const* d_in, const int* in_sizes, int n_in,
                              void* d_out, int out_size, void* d_ws, size_t ws_size,
                              hipStream_t stream) {
    const float* x   = (const float*)d_in[0];  // (B,T,C) fp32
    const float* n1w = (const float*)d_in[1];  // (C)
    const float* w1  = (const float*)d_in[2];  // (C,C)
    const float* b1  = (const float*)d_in[3];  // (C)
    const float* n2w = (const float*)d_in[4];  // (C)
    const float* w21 = (const float*)d_in[5];  // (C,E)
    const float* b21 = (const float*)d_in[6];  // (E)
    const float* w22 = (const float*)d_in[7];  // (E,C)
    const float* b22 = (const float*)d_in[8];  // (C)
    float* out = (float*)d_out;                // (B,T,C) fp32

    char* ws = (char*)d_ws;
    const size_t MB = 1024ull * 1024ull;
    unsigned short* state = (unsigned short*)(ws);            // 32MB bf16; reused as hnorm
    unsigned short* w1T   = (unsigned short*)(ws + 32 * MB);  // 2MB  (C x C) bf16
    unsigned short* w21T  = (unsigned short*)(ws + 34 * MB);  // 8MB  (E x C) bf16
    unsigned short* w22T  = (unsigned short*)(ws + 42 * MB);  // 8MB  (C x E) bf16
    float* P              = (float*)(ws + 50 * MB);           // 1MB
    float* rinv           = (float*)(ws + 51 * MB);           // 64KB
    unsigned short* h     = (unsigned short*)(ws + 52 * MB);  // up to 128MB bf16 (sliced)
    float* out1 = out;  // gate*x lives in d_out (fp32); G3 reads then overwrites per-element

    // pick M-slice size for the h buffer based on available workspace
    int slice_rows = Mdim;  // 16384 -> h=128MB (total 180MB); halve until it fits
    while (52 * MB + (size_t)slice_rows * Edim * 2 > ws_size && slice_rows > 1024)
        slice_rows >>= 1;

    // weights -> bf16 (N x K)
    transpose_f2b<<<dim3(Cdim / 32, Cdim / 32), 256, 0, stream>>>(w1, w1T, Cdim, Cdim);
    transpose_f2b<<<dim3(Edim / 32, Cdim / 32), 256, 0, stream>>>(w21, w21T, Cdim, Edim);
    transpose_f2b<<<dim3(Cdim / 32, Edim / 32), 256, 0, stream>>>(w22, w22T, Edim, Cdim);

    // rmsnorm1 scale factors
    rms_inv_kernel<<<Mdim, 256, 0, stream>>>(x, rinv);

    // chunked cumsum of x*rinv*n1w over T, with triangular scaler -> bf16 state
    chunk_sums<<<1024, 256, 0, stream>>>(x, rinv, n1w, P);
    chunk_scan<<<32, 256, 0, stream>>>(P);
    cumsum_state<<<1024, 256, 0, stream>>>(x, rinv, n1w, P, state);

    // G1: out1 = sigmoid(state @ w1 + b1) * x   (fp32 out into d_out)
    gemm8<0><<<dim3((Mdim / 256) * (Cdim / 256)), 512, 0, stream>>>(
        state, w1T, b1, x, out1, Cdim, Cdim);

    // rmsnorm2(out1) -> bf16 hnorm (reuse state buffer)
    rmsnorm_f2b<<<Mdim, 256, 0, stream>>>(out1, n2w, state);

    // G2/G3 sliced over M to bound the h buffer
    for (int m0 = 0; m0 < Mdim; m0 += slice_rows) {
        gemm8<1><<<dim3((slice_rows / 256) * (Edim / 256)), 512, 0, stream>>>(
            state + (size_t)m0 * Cdim, w21T, b21, nullptr, h, Edim, Cdim);
        gemm8<2><<<dim3((slice_rows / 256) * (Cdim / 256)), 512, 0, stream>>>(
            h, w22T, b22, out1 + (size_t)m0 * Cdim, out + (size_t)m0 * Cdim,
            Cdim, Edim);
    }
}